// Round 1
// baseline (80.456 us; speedup 1.0000x reference)
//
#include <hip/hip_runtime.h>

// Problem constants
#define HD    768
#define NOUT  72      // R*3
#define LSEQ  8256
#define RREL  24
#define BMT   128     // M-tile (66048 / 128 = 516 blocks exactly)
#define BKT   32      // K-step
#define KSTEPS 24     // 768 / 32
#define NTILES 5      // ceil(72/16) -> padded to 80

typedef float  f32x4 __attribute__((ext_vector_type(4)));
typedef short  s16x8 __attribute__((ext_vector_type(8)));
typedef unsigned short u16x4 __attribute__((ext_vector_type(4)));

// LDS: staging buffers (K-loop) union'd with logits buffer (epilogue)
union SharedU {
  struct {
    unsigned short A[BMT][BKT];        // 8 KB  [row][k], 16B-slot XOR swizzle
    unsigned short Bf[NTILES][64][8];  // 5 KB  fragment-order: [nt][lane][i]
  } s;
  float logits[64][81];                // 20.25 KB, stride 81 to spread banks
};

__device__ __forceinline__ unsigned short f2bf(float f) {
  // round-to-nearest-even fp32 -> bf16 (inputs are finite randn; no NaN path)
  unsigned int b = __builtin_bit_cast(unsigned int, f);
  b += 0x7FFFu + ((b >> 16) & 1u);
  return (unsigned short)(b >> 16);
}

__global__ __launch_bounds__(256, 4)
void tagging_kernel(const float* __restrict__ hs, const float* __restrict__ W,
                    const float* __restrict__ bias, float* __restrict__ out) {
  __shared__ SharedU sh;
  __shared__ float biasS[NOUT];

  const int tid  = threadIdx.x;
  const int lane = tid & 63;
  const int w    = tid >> 6;           // wave id 0..3, owns rows [32w, 32w+32)
  const int m0   = blockIdx.x * BMT;

  if (tid < NOUT) biasS[tid] = bias[tid];

  f32x4 acc[2][NTILES] = {};           // 2 m-subtiles x 5 n-tiles, f32x4 each

  const int lrow = lane & 15;          // A/B frag: dim index
  const int loct = lane >> 4;          // A/B frag: k-oct (8 contiguous k)

  for (int ks = 0; ks < KSTEPS; ++ks) {
    const int k0 = ks * BKT;
    __syncthreads();                   // previous iteration's frag reads done

    // ---- stage A: 128 rows x 32 floats = 1024 float4, 4 per thread ----
    #pragma unroll
    for (int it = 0; it < 4; ++it) {
      int idx = it * 256 + tid;        // [0,1024)
      int row = idx >> 3;              // 8 float4 per row
      int q   = idx & 7;               // which float4 in the row
      float4 v = *(const float4*)(hs + (size_t)(m0 + row) * HD + k0 + q * 4);
      u16x4 c;
      c[0] = f2bf(v.x); c[1] = f2bf(v.y); c[2] = f2bf(v.z); c[3] = f2bf(v.w);
      // 16B-slot swizzle: physical oct = logical oct ^ ((row>>1)&3)
      int oct = (q >> 1) ^ ((row >> 1) & 3);
      *(u16x4*)(&sh.s.A[0][0] + row * BKT + oct * 8 + (q & 1) * 4) = c;
    }

    // ---- stage B (W slice) in fragment order: 72 rows x 32 floats = 576 float4 ----
    #pragma unroll
    for (int it = 0; it < 3; ++it) {
      int idx = it * 256 + tid;
      if (idx < 576) {
        int n = idx >> 3;              // output column 0..71
        int q = idx & 7;
        float4 v = *(const float4*)(W + (size_t)n * HD + k0 + q * 4);
        u16x4 c;
        c[0] = f2bf(v.x); c[1] = f2bf(v.y); c[2] = f2bf(v.z); c[3] = f2bf(v.w);
        int bl = (n & 15) + ((q >> 1) << 4);   // frag lane = (n&15) + 16*oct
        *(u16x4*)&sh.s.Bf[n >> 4][bl][(q & 1) * 4] = c;
      }
      // tail n-tile cols 72..79 never written; Bf is re-written every k-step but
      // those lanes read whatever was there -> must be zero. Zero them once below.
    }
    // zero the pad lanes of the last n-tile (cols 72..79): lanes with (l&15)>=8
    if (tid < 32) {                    // 32 pad (oct,colsub) slots: 4 octs x 8 cols
      int oct = tid >> 3, c8 = (tid & 7) + 8;
      *(u16x4*)&sh.s.Bf[4][c8 + (oct << 4)][0] = (u16x4){0,0,0,0};
      *(u16x4*)&sh.s.Bf[4][c8 + (oct << 4)][4] = (u16x4){0,0,0,0};
    }
    __syncthreads();

    // ---- fragments + MFMA ----
    s16x8 bfr[NTILES];
    #pragma unroll
    for (int nt = 0; nt < NTILES; ++nt)
      bfr[nt] = *(const s16x8*)&sh.s.Bf[nt][lane][0];
    #pragma unroll
    for (int mt = 0; mt < 2; ++mt) {
      int row = w * 32 + mt * 16 + lrow;
      int oct = loct ^ ((row >> 1) & 3);
      s16x8 afr = *(const s16x8*)(&sh.s.A[0][0] + row * BKT + oct * 8);
      #pragma unroll
      for (int nt = 0; nt < NTILES; ++nt)
        acc[mt][nt] = __builtin_amdgcn_mfma_f32_16x16x32_bf16(
            afr, bfr[nt], acc[mt][nt], 0, 0, 0);
    }
  }

  // ---- epilogue: two 64-row passes through LDS, softmax over triples ----
  #pragma unroll
  for (int pass = 0; pass < 2; ++pass) {
    __syncthreads();                   // staging reads / prev softmax reads done
    if ((w >> 1) == pass) {
      int wl = w & 1;                  // wave's 32-row half within this 64-row pass
      #pragma unroll
      for (int mt = 0; mt < 2; ++mt)
        #pragma unroll
        for (int nt = 0; nt < NTILES; ++nt)
          #pragma unroll
          for (int j = 0; j < 4; ++j) {
            // C/D layout: col = lane&15, row = 4*(lane>>4)+j  [guide-verified]
            int lr  = wl * 32 + mt * 16 + (lane >> 4) * 4 + j;
            int col = nt * 16 + (lane & 15);   // up to 79 < 81, in-bounds
            sh.logits[lr][col] = acc[mt][nt][j];
          }
    }
    __syncthreads();
    #pragma unroll
    for (int it = 0; it < 6; ++it) {
      int flat = it * 256 + tid;       // [0,1536) = 24 triples x 64 tokens
      int g    = flat >> 6;            // relation r, wave-uniform
      int tokl = flat & 63;
      int tok  = m0 + pass * 64 + tokl;
      int bidx = tok / LSEQ;
      int l    = tok - bidx * LSEQ;
      float x0 = sh.logits[tokl][g * 3 + 0] + biasS[g * 3 + 0];
      float x1 = sh.logits[tokl][g * 3 + 1] + biasS[g * 3 + 1];
      float x2 = sh.logits[tokl][g * 3 + 2] + biasS[g * 3 + 2];
      float mx = fmaxf(x0, fmaxf(x1, x2));
      float e0 = __expf(x0 - mx), e1 = __expf(x1 - mx), e2 = __expf(x2 - mx);
      float inv = 1.0f / (e0 + e1 + e2);
      size_t o = ((size_t)(bidx * RREL + g) * LSEQ + l) * 3;
      out[o + 0] = e0 * inv;
      out[o + 1] = e1 * inv;
      out[o + 2] = e2 * inv;
    }
  }
}

extern "C" void kernel_launch(void* const* d_in, const int* in_sizes, int n_in,
                              void* d_out, int out_size, void* d_ws, size_t ws_size,
                              hipStream_t stream) {
  (void)in_sizes; (void)n_in; (void)d_ws; (void)ws_size; (void)out_size;
  const float* hs   = (const float*)d_in[0];  // (8, 8256, 768) fp32
  const float* W    = (const float*)d_in[1];  // (24, 3, 768)   fp32
  const float* bias = (const float*)d_in[2];  // (24, 3)        fp32
  float* out = (float*)d_out;                 // (8, 24, 8256, 3) fp32

  dim3 grid(66048 / BMT);                     // 516 blocks, exact
  dim3 block(256);
  hipLaunchKernelGGL(tagging_kernel, grid, block, 0, stream, hs, W, bias, out);
}